// Round 4
// baseline (258.224 us; speedup 1.0000x reference)
//
#include <hip/hip_runtime.h>
#include <hip/hip_bf16.h>
#include <stdint.h>

#define N_REP 8
#define BATCH 32
#define NIN   128
#define NOUT  128
#define EDIM  1024
#define MDIM  130
#define ETILE 64
#define SE    68    // LDS row stride (dwords): 64 data + 4 pad; 16B-aligned rows,
                    // frag-read lanes (q,r) -> banks {16q + r} mod 32 = exact 2-way (free)

typedef __attribute__((ext_vector_type(8))) short short8;
typedef __attribute__((ext_vector_type(4))) float f32x4;

__device__ __forceinline__ unsigned short f2bf(float f) {
    union { float f; uint32_t u; } v;
    v.f = f;
    uint32_t u = v.u;
    uint32_t r = u + 0x7fffu + ((u >> 16) & 1u);   // RNE
    return (unsigned short)(r >> 16);
}

__device__ __forceinline__ uint32_t pk2bf(float lo, float hi) {
    __hip_bfloat162 h = __float22bfloat162_rn(make_float2(lo, hi)); // .x -> low16
    uint32_t d;
    __builtin_memcpy(&d, &h, 4);
    return d;
}

// One wave per (n,o). m parallel across lanes: m = lane, lane+64, (lane<2: 128+lane).
// Emits S[n][o][m] = W*sign (bf16, K-minor) and bias[n][o] = sum Wneg(m<128) + Wpos(m=128).
__global__ __launch_bounds__(64)
void prep_kernel(const float* __restrict__ theta,
                 const float* __restrict__ noise,
                 unsigned short* __restrict__ Sg,
                 float* __restrict__ biasg) {
    const int n = blockIdx.x >> 7;
    const int o = blockIdx.x & 127;
    const int lane = threadIdx.x;

    const float* nb = noise + (size_t)n * MDIM * NOUT + o;
    auto tn_at = [&](int m) -> float {
        float t = theta[m * NOUT + o];
        t = fminf(fmaxf(t, -1.f), 1.f);
        if (fabsf(t) < 0.01f) t = 0.f;
        return t * fmaf(nb[m * NOUT], 0.2f, 0.9f);
    };

    const float t0 = tn_at(lane);
    const float t1 = tn_at(lane + 64);
    const float t2 = (lane < 2) ? tn_at(128 + lane) : 0.f;

    float s = fabsf(t0) + fabsf(t1) + fabsf(t2);
#pragma unroll
    for (int d = 1; d < 64; d <<= 1) s += __shfl_xor(s, d, 64);
    const float inv = 1.f / (s + 1e-10f);

    const float w0 = fabsf(t0) * inv, w1 = fabsf(t1) * inv;
    unsigned short* srow = Sg + ((size_t)n * NOUT + o) * NIN;
    srow[lane]      = f2bf(t0 >= 0.f ? w0 : -w0);
    srow[lane + 64] = f2bf(t1 >= 0.f ? w1 : -w1);

    float b = (t0 < 0.f ? w0 : 0.f) + (t1 < 0.f ? w1 : 0.f);
    if (lane == 0 && t2 >= 0.f) b += fabsf(t2) * inv;   // ones-column positive part
#pragma unroll
    for (int d = 1; d < 64; d <<= 1) b += __shfl_xor(b, d, 64);
    if (lane == 0) biasg[n * NOUT + o] = b;
}

// out[nb][o][e] = tanh-act( sum_m a[nb][m][e] * S[n][o][m] + bias[n][o] ).
// 128-thread blocks, tile [m=128][e=64], bf16 m-pair-packed LDS (17408 B) ->
// 8 blocks/CU, 16 waves/CU: 8 independent phase-domains per CU so some blocks'
// reads overlap others' compute/writes (latency-bound fix; DMA/pipeline variants
// measured worse - compiler drains vmcnt(0) before ds_read after global_load_lds).
// Staging: 16 back-to-back float4 loads per thread (max MLP), then pack+ds_write.
// MFMA: A = a-frag (rows=e), B = S -> lane owns 4 consecutive e -> float4 stores.
__global__ __launch_bounds__(128, 4)
void gemm_kernel(const float* __restrict__ a,
                 const unsigned short* __restrict__ Sg,
                 const float* __restrict__ biasg,
                 const float* __restrict__ eta,
                 float* __restrict__ out) {
    __shared__ uint32_t Alds[64 * SE];               // 17408 B
    const int bid  = blockIdx.x;
    const int et   = bid & 15;                       // e-tile (64 wide)
    const int nb   = bid >> 4;                       // n*B + b
    const int n    = nb >> 5;
    const int tid  = threadIdx.x;
    const int lane = tid & 63;
    const int w    = tid >> 6;                       // 2 waves, split over o
    const int r    = lane & 15;
    const int q    = lane >> 4;

    // ---- stage: fp32 [m=128][e=64] -> bf16 m-pair dwords [mp=64][e=64] ----
    {
        const float* abase = a + (size_t)nb * (NIN * EDIM) + et * ETILE;
        const int e4  = (tid & 15) << 2;             // 16 threads cover 64 e
        const int mp0 = tid >> 4;                    // 0..7
        float4 va[8], vb[8];
#pragma unroll
        for (int it = 0; it < 8; ++it) {
            const int mp = mp0 + (it << 3);
            va[it] = *(const float4*)(abase + (size_t)(2 * mp) * EDIM + e4);
            vb[it] = *(const float4*)(abase + (size_t)(2 * mp + 1) * EDIM + e4);
        }
#pragma unroll
        for (int it = 0; it < 8; ++it) {
            const int mp = mp0 + (it << 3);
            uint4 d;
            d.x = pk2bf(va[it].x, vb[it].x);
            d.y = pk2bf(va[it].y, vb[it].y);
            d.z = pk2bf(va[it].z, vb[it].z);
            d.w = pk2bf(va[it].w, vb[it].w);
            *(uint4*)&Alds[mp * SE + e4] = d;
        }
    }
    __syncthreads();

    const int o_base = w << 6;

    // eta scalars forced into VGPRs: avoids two-SGPR VOP3 (constant-bus violation)
    float e0 = eta[0], e1 = eta[1], e2 = eta[2], e3 = eta[3];
    asm volatile("" : "+v"(e0), "+v"(e1), "+v"(e2), "+v"(e3));
    float bl[4];
#pragma unroll
    for (int fo = 0; fo < 4; ++fo)
        bl[fo] = biasg[n * NOUT + o_base + (fo << 4) + r];

    f32x4 acc[4][4];                                 // [fo][fe]
#pragma unroll
    for (int fo = 0; fo < 4; ++fo)
#pragma unroll
        for (int fe = 0; fe < 4; ++fe)
            acc[fo][fe] = (f32x4){0.f, 0.f, 0.f, 0.f};

    const unsigned short* sbase = Sg + ((size_t)(n * NOUT) << 7) + (q << 3);
#pragma unroll
    for (int ks = 0; ks < 4; ++ks) {
        // S fragments (B-operand): 16 B contiguous from global (L2-hot, 32 KiB/n)
        short8 sf[4];
#pragma unroll
        for (int fo = 0; fo < 4; ++fo)
            sf[fo] = *(const short8*)(sbase + ((size_t)(o_base + (fo << 4) + r) << 7)
                                             + (ks << 5));
        // a fragments (A-operand): 4 dwords, dword = 2 consecutive-k bf16;
        // lanes (q,r) -> banks {16q + r}: exact 2-way aliasing (free)
        const int mpb = (ks << 4) + (q << 2);
        short8 af[4];
#pragma unroll
        for (int fe = 0; fe < 4; ++fe) {
            uint32_t d[4];
#pragma unroll
            for (int jj = 0; jj < 4; ++jj)
                d[jj] = Alds[(mpb + jj) * SE + (fe << 4) + r];
            __builtin_memcpy(&af[fe], d, 16);
        }
#pragma unroll
        for (int fo = 0; fo < 4; ++fo)
#pragma unroll
            for (int fe = 0; fe < 4; ++fe)
                acc[fo][fe] = __builtin_amdgcn_mfma_f32_16x16x32_bf16(
                    af[fe], sf[fo], acc[fo][fe], 0, 0, 0);
    }

    // ---- epilogue: bias + printed tanh; lane owns 4 consecutive e -> float4 ----
    float* obase = out + (size_t)nb * (NOUT * EDIM) + et * ETILE;
#pragma unroll
    for (int fo = 0; fo < 4; ++fo) {
        float* orow = obase + (size_t)(o_base + (fo << 4) + r) * EDIM;
        const float bv = bl[fo];
#pragma unroll
        for (int fe = 0; fe < 4; ++fe) {
            f32x4 res;
#pragma unroll
            for (int i = 0; i < 4; ++i) {
                const float z = acc[fo][fe][i] + bv;
                const float y = (z - e2) * e3;
                const float ex = __expf(2.f * y);
                const float th = 1.f - 2.f * __builtin_amdgcn_rcpf(ex + 1.f);
                res[i] = fmaf(e1, th, e0);
            }
            *(f32x4*)(orow + (fe << 4) + (q << 2)) = res;
        }
    }
}

extern "C" void kernel_launch(void* const* d_in, const int* in_sizes, int n_in,
                              void* d_out, int out_size, void* d_ws, size_t ws_size,
                              hipStream_t stream) {
    const float* a     = (const float*)d_in[0];
    const float* theta = (const float*)d_in[1];
    const float* noise = (const float*)d_in[2];
    const float* eta   = (const float*)d_in[3];
    float* out = (float*)d_out;

    unsigned short* Sg = (unsigned short*)d_ws;      // 8*128*128 bf16 = 256 KiB
    float* biasg = (float*)((char*)d_ws + (size_t)N_REP * NOUT * NIN * sizeof(unsigned short));

    prep_kernel<<<N_REP * NOUT, 64, 0, stream>>>(theta, noise, Sg, biasg);
    gemm_kernel<<<N_REP * BATCH * (EDIM / ETILE), 128, 0, stream>>>(a, Sg, biasg, eta, out);
}